// Round 4
// baseline (224.039 us; speedup 1.0000x reference)
//
#include <hip/hip_runtime.h>

#define S_LEN  2048
#define NH     16
#define HD     64
#define DMODEL 1024

using bf16x8 = __attribute__((ext_vector_type(8))) __bf16;
using f32x4  = __attribute__((ext_vector_type(4))) float;

__device__ __forceinline__ unsigned short f2bf(float f) {
    unsigned u = __float_as_uint(f);
    u += 0x7FFFu + ((u >> 16) & 1u);   // RNE
    return (unsigned short)(u >> 16);
}
// pack trunc(a)->lo, trunc(b)->hi in one v_perm
__device__ __forceinline__ unsigned pk_trunc(float lo, float hi) {
    return __builtin_amdgcn_perm(__float_as_uint(hi), __float_as_uint(lo), 0x07060302u);
}

// raw v_exp_f32 (2^x); avoids OCML fixup sequence. Underflow flushes to 0 (wanted).
#define EXP2(x) __builtin_amdgcn_exp2f(x)

// async global->LDS, 16B per lane; dest = wave-uniform base + lane*16
#define GLDS16(gsrc, ldst) \
    __builtin_amdgcn_global_load_lds((__attribute__((address_space(1))) void*)(gsrc), \
                                     (__attribute__((address_space(3))) void*)(ldst), 16, 0, 0)

#define WAIT_LGKM0() __builtin_amdgcn_s_waitcnt(0xC07F)   // lgkmcnt(0) only

// counted vmcnt + raw barrier (no implicit drain); memory clobber pins ordering
#define ASM_VMCNT(n)  asm volatile("s_waitcnt vmcnt(" #n ")" ::: "memory")
#define ASM_BARRIER() asm volatile("s_barrier" ::: "memory")

// ---------------------------------------------------------------------------
// Fused prep: x fp32->bf16 (blocks 0..4095), weight transpose+convert
// (blocks 4096..8191). No fences/atomics.
// ---------------------------------------------------------------------------
__global__ __launch_bounds__(256) void prep_kernel(
    const float* __restrict__ x, const float* __restrict__ w_qkv,
    const float* __restrict__ w_out,
    unsigned short* __restrict__ xb, unsigned short* __restrict__ wqkvT,
    unsigned short* __restrict__ woutT) {
    __shared__ float T[32][33];
    int bx = blockIdx.x;
    if (bx < 4096) {
        int idx = (bx * 256 + threadIdx.x) * 4;
        float4 v = *(const float4*)(x + idx);
        ushort4 o;
        o.x = f2bf(v.x); o.y = f2bf(v.y); o.z = f2bf(v.z); o.w = f2bf(v.w);
        *(ushort4*)(xb + idx) = o;
        return;
    }
    int tb = bx - 4096;
    int tcol = tb & 127, krow = tb >> 7;
    const float* in;
    unsigned short* out;
    int N, nbx;
    if (tcol < 96) { in = w_qkv; out = wqkvT; N = 3072; nbx = tcol; }
    else           { in = w_out; out = woutT; N = 1024; nbx = tcol - 96; }
    int r  = threadIdx.x >> 3;
    int c4 = (threadIdx.x & 7) * 4;
    int kbase = krow * 32, nbase = nbx * 32;
    float4 v = *(const float4*)(in + (size_t)(kbase + r) * N + nbase + c4);
    T[r][c4 + 0] = v.x; T[r][c4 + 1] = v.y; T[r][c4 + 2] = v.z; T[r][c4 + 3] = v.w;
    __syncthreads();
    ushort4 o;
    o.x = f2bf(T[c4 + 0][r]); o.y = f2bf(T[c4 + 1][r]);
    o.z = f2bf(T[c4 + 2][r]); o.w = f2bf(T[c4 + 3][r]);
    *(ushort4*)(out + (size_t)(nbase + r) * 1024 + kbase + c4) = o;
}

// ---------------------------------------------------------------------------
// MFMA NT GEMM mainloop, BK=64, tile 128 x (NI*32). A: LDS double-buffered
// via global_load_lds (XOR-swizzled). B: DIRECT global->VGPR fragments
// (weights are L2-resident per-XCD strips; skipping LDS halves LDS traffic).
// 2-phase pipeline, counted vmcnt (A(t+1) 4 GLDS + B(t+1) loads in flight).
// ---------------------------------------------------------------------------
template <int NI>
__device__ __forceinline__ void mfma_mainloop_bd(
    const unsigned short* __restrict__ A, const unsigned short* __restrict__ B,
    int K, int m0, int n0, unsigned short* As, f32x4 acc[4][NI]) {
    const int lane = threadIdx.x & 63, wave = threadIdx.x >> 6;
    const int quad = lane >> 4, l15 = lane & 15;
    const int wm0 = (wave >> 1) * 64, wn0 = (wave & 1) * (NI * 16);
    const int nt = K >> 6;   // even (K=1024 -> 16)
    const unsigned short* Bw = B + (size_t)(n0 + wn0 + l15) * K + quad * 8;

#define STAGE_A(k0, b) { \
    unsigned short* Ad = As + (b) * 8192; \
    _Pragma("unroll") \
    for (int j = 0; j < 4; ++j) { \
        int c0 = j * 256 + wave * 64; \
        int c  = c0 + lane; \
        int r = c >> 3, pc = c & 7, q = pc ^ (r & 7); \
        GLDS16(A + (size_t)(m0 + r) * K + (k0) + q * 8, Ad + c0 * 8); \
    } }

#define LOAD_B(k0, br) { \
    _Pragma("unroll") \
    for (int ni = 0; ni < NI; ++ni) { \
        br[0][ni] = *(const bf16x8*)(Bw + (size_t)(ni * 16) * K + (k0)); \
        br[1][ni] = *(const bf16x8*)(Bw + (size_t)(ni * 16) * K + (k0) + 32); \
    } }

#define COMPUTE(b, br) { \
    const unsigned short* Ab = As + (b) * 8192; \
    bf16x8 af[2][4]; \
    _Pragma("unroll") \
    for (int mi = 0; mi < 4; ++mi) { \
        int r = wm0 + mi * 16 + l15, x = r & 7; \
        af[0][mi] = *(const bf16x8*)(Ab + r * 64 + ((quad    ) ^ x) * 8); \
        af[1][mi] = *(const bf16x8*)(Ab + r * 64 + ((4 + quad) ^ x) * 8); \
    } \
    _Pragma("unroll") \
    for (int h = 0; h < 2; ++h) \
        _Pragma("unroll") \
        for (int mi = 0; mi < 4; ++mi) \
            _Pragma("unroll") \
            for (int ni = 0; ni < NI; ++ni) \
                acc[mi][ni] = __builtin_amdgcn_mfma_f32_16x16x32_bf16( \
                    af[h][mi], br[h][ni], acc[mi][ni], 0, 0, 0); }

    bf16x8 brX[2][NI], brY[2][NI];
    STAGE_A(0, 0);
    LOAD_B(0, brX);
    for (int t = 0; t < nt; t += 2) {
        STAGE_A((t + 1) * 64, 1);
        LOAD_B((t + 1) * 64, brY);
        if constexpr (NI == 4) { ASM_VMCNT(12); } else { ASM_VMCNT(8); }
        ASM_BARRIER();                       // A(t) landed for all waves
        COMPUTE(0, brX);
        ASM_BARRIER();                       // buf0 fully read
        if (t + 2 < nt) {
            STAGE_A((t + 2) * 64, 0);
            LOAD_B((t + 2) * 64, brX);
            if constexpr (NI == 4) { ASM_VMCNT(12); } else { ASM_VMCNT(8); }
        } else {
            ASM_VMCNT(0);
        }
        ASM_BARRIER();
        COMPUTE(1, brY);
        ASM_BARRIER();
    }
#undef STAGE_A
#undef LOAD_B
#undef COMPUTE
}

// ---------------------------------------------------------------------------
// GEMM1: qkv projection, 768 blocks, XCD-swizzled tiles: xcd owns n-strip
// [xcd*3, xcd*3+3) (B strip 768KB -> one L2). Epilogue: LDS transpose ->
// dwordx4 stores. Q -> Qt [bh][d][s] PRE-SCALED by 1/sqrt(64)*log2e,
// K -> Kh [bh][s][d], V -> Vt [bh][d][s].
// ---------------------------------------------------------------------------
__global__ __launch_bounds__(256) void gemm_qkv_kernel(
    const unsigned short* __restrict__ xb, const unsigned short* __restrict__ wT,
    const float* __restrict__ bias,
    unsigned short* __restrict__ Qt, unsigned short* __restrict__ Kh,
    unsigned short* __restrict__ Vt) {
    __shared__ __align__(16) unsigned short Sh[16384];  // As dbuf (2x8192)
    unsigned short* As = Sh;

    f32x4 acc[4][4];
    #pragma unroll
    for (int i = 0; i < 4; ++i)
        #pragma unroll
        for (int j = 0; j < 4; ++j) acc[i][j] = (f32x4){0.f, 0.f, 0.f, 0.f};

    const int bid = blockIdx.x;
    const int xcd = bid & 7, slot = bid >> 3;          // slot 0..95
    const int nt = xcd * 3 + (slot % 3);               // 0..23
    const int mt = slot / 3;                           // 0..31
    const int m0 = mt * 128, n0 = nt * 128;
    mfma_mainloop_bd<4>(xb, wT, DMODEL, m0, n0, As, acc);

    const int lane = threadIdx.x & 63, wave = threadIdx.x >> 6;
    const int quad = lane >> 4, l15 = lane & 15;
    const int wm0 = (wave >> 1) * 64, wn0 = (wave & 1) * 64;

    const int colbase = n0 + wn0;            // 64-aligned -> uniform t,h per wave
    const int t = colbase >> 10;
    const int h = (colbase >> 6) & (NH - 1);
    const float qscale = (t == 0) ? 0.125f * 1.44269504088896f : 1.0f;
    float bv[4];
    #pragma unroll
    for (int ni = 0; ni < 4; ++ni) bv[ni] = bias[colbase + ni * 16 + l15];

    __syncthreads();                         // everyone done reading As
    unsigned short* Lw = Sh + wave * 1536;   // per-wave scratch (3 KB)

    #pragma unroll
    for (int mi = 0; mi < 4; ++mi) {
        int mbase = m0 + wm0 + mi * 16;
        int b = mbase >> 11, sbase = mbase & (S_LEN - 1);
        if (t == 1) {
            // K: want [s][d] rows; Lw[r*72 + c]
            #pragma unroll
            for (int ni = 0; ni < 4; ++ni)
                #pragma unroll
                for (int r = 0; r < 4; ++r)
                    Lw[(quad * 4 + r) * 72 + ni * 16 + l15] =
                        f2bf(acc[mi][ni][r] + bv[ni]);
            WAIT_LGKM0();
            int rr = lane & 15, dc = (lane >> 4) * 16;
            uint4 v0 = *(const uint4*)(Lw + rr * 72 + dc);
            uint4 v1 = *(const uint4*)(Lw + rr * 72 + dc + 8);
            unsigned short* dst =
                Kh + ((size_t)(b * NH + h) * S_LEN + sbase + rr) * HD + dc;
            *(uint4*)dst = v0;
            *(uint4*)(dst + 8) = v1;
        } else {
            // Q/V: want [d][s] rows; Lw[c*24 + r]
            #pragma unroll
            for (int ni = 0; ni < 4; ++ni)
                #pragma unroll
                for (int r = 0; r < 4; ++r)
                    Lw[(ni * 16 + l15) * 24 + quad * 4 + r] =
                        f2bf((acc[mi][ni][r] + bv[ni]) * qscale);
            WAIT_LGKM0();
            int c = lane;                    // d within head
            uint4 v0 = *(const uint4*)(Lw + c * 24);
            uint4 v1 = *(const uint4*)(Lw + c * 24 + 8);
            unsigned short* base = (t == 0) ? Qt : Vt;
            unsigned short* dst =
                base + ((size_t)(b * NH + h) * HD + c) * S_LEN + sbase;
            *(uint4*)dst = v0;
            *(uint4*)(dst + 8) = v1;
        }
        WAIT_LGKM0();                        // stores consumed Lw before next mi
    }
}

// ---------------------------------------------------------------------------
// GEMM3: out = zb @ w_outT + b_out, fp32. 128x64 tiles -> 512 blocks,
// XCD-swizzled: xcd owns n-tiles [2*xcd, 2*xcd+2) (B strip 256KB in L2).
// ---------------------------------------------------------------------------
__global__ __launch_bounds__(256) void gemm_out_kernel(
    const unsigned short* __restrict__ zb, const unsigned short* __restrict__ wT,
    const float* __restrict__ bias, float* __restrict__ out) {
    __shared__ __align__(16) unsigned short As[16384];  // dbuf
    f32x4 acc[4][2];
    #pragma unroll
    for (int i = 0; i < 4; ++i)
        #pragma unroll
        for (int j = 0; j < 2; ++j) acc[i][j] = (f32x4){0.f, 0.f, 0.f, 0.f};

    const int bid = blockIdx.x;
    const int xcd = bid & 7, slot = bid >> 3;          // slot 0..63
    const int nt = xcd * 2 + (slot & 1);               // 0..15 (64-wide)
    const int mt = slot >> 1;                          // 0..31
    const int m0 = mt * 128, n0 = nt * 64;
    mfma_mainloop_bd<2>(zb, wT, DMODEL, m0, n0, As, acc);

    const int lane = threadIdx.x & 63, wave = threadIdx.x >> 6;
    const int quad = lane >> 4, l15 = lane & 15;
    const int wm0 = (wave >> 1) * 64, wn0 = (wave & 1) * 32;
    #pragma unroll
    for (int mi = 0; mi < 4; ++mi) {
        #pragma unroll
        for (int ni = 0; ni < 2; ++ni) {
            int col = n0 + wn0 + ni * 16 + l15;
            float bvv = bias[col];
            #pragma unroll
            for (int r = 0; r < 4; ++r)
                out[(size_t)(m0 + wm0 + mi * 16 + quad * 4 + r) * DMODEL + col] =
                    acc[mi][ni][r] + bvv;
        }
    }
}

// ---------------------------------------------------------------------------
// Balanced causal schedule for QBLK=128: 24 entries {qt, kt_lo, kt_hi, part},
// size-descending. qt 8..15 split into halves (part 0/1); qt 0..7 unsplit.
// ---------------------------------------------------------------------------
__device__ const int g_sched[24 * 4] = {
    15,0,15,0,  15,16,31,1,  7,0,15,-1,
    14,0,14,0,  14,15,29,1,  6,0,13,-1,
    13,0,13,0,  13,14,27,1,
    12,0,12,0,  12,13,25,1,  5,0,11,-1,
    11,0,11,0,  11,12,23,1,
    10,0,10,0,  10,11,21,1,  4,0,9,-1,
     9,0,9,0,    9,10,19,1,
     8,0,8,0,    8,9,17,1,   3,0,7,-1,
     2,0,5,-1,   1,0,3,-1,   0,0,1,-1
};

// ---------------------------------------------------------------------------
// Flash attention, S^T orientation: S^T = K Q^T, Z^T = V^T P. Fixed-max
// softmax (Q pre-scaled, acc init -M0). QBLK=128, 8 waves; K/V LDS
// double-buffered, counted-vmcnt 2-phase pipeline, kt-loop unrolled by 2
// (literal buffer bases), raw v_exp_f32, setprio around MFMA clusters.
// Causal: for k-tile kt, kq = kt-2*qt; dw = wave-4*kq (<0 => wave fully
// masked, skip); nmax=min(dw,3), khmax=min(dw>>1,1).
// ---------------------------------------------------------------------------
__global__ __launch_bounds__(512) void attn_mfma_kernel(
    const unsigned short* __restrict__ Qt, const unsigned short* __restrict__ Kh,
    const unsigned short* __restrict__ Vt, unsigned short* __restrict__ zb,
    float* __restrict__ Zp, float* __restrict__ lp) {
    __shared__ __align__(16) unsigned short Ks[2 * 64 * 64]; // [key][d], swizzled, dbuf
    __shared__ __align__(16) unsigned short Vs[2 * 64 * 64]; // [d][key], swizzled, dbuf
    __shared__ __align__(16) unsigned short Pl[8 * 16 * 64]; // per-wave P, swizzled

    const int lane = threadIdx.x & 63, wave = threadIdx.x >> 6;   // wave 0..7
    const int quad = lane >> 4, l15 = lane & 15;
    const int bh = blockIdx.x;
    const int qt   = g_sched[blockIdx.y * 4 + 0];
    const int klo  = g_sched[blockIdx.y * 4 + 1];
    const int khi  = g_sched[blockIdx.y * 4 + 2];
    const int part = g_sched[blockIdx.y * 4 + 3];
    const int q0 = qt * 128;
    const float M0 = 12.0f;                  // fixed max (log2 domain)

    // ---- Q B-frags from Qt [bh][d][s] (pre-scaled): lane = q column ----
    bf16x8 qf0, qf1;
    {
        const unsigned short* qb = Qt + (size_t)bh * HD * S_LEN + q0 + wave * 16 + l15;
        union { bf16x8 v; unsigned short u[8]; } u0, u1;
        #pragma unroll
        for (int j = 0; j < 8; ++j) {
            u0.u[j] = qb[(quad * 8 + j) * S_LEN];
            u1.u[j] = qb[(32 + quad * 8 + j) * S_LEN];
        }
        qf0 = u0.v; qf1 = u1.v;
    }

    f32x4 Z[4];
    #pragma unroll
    for (int i = 0; i < 4; ++i) Z[i] = (f32x4){0.f, 0.f, 0.f, 0.f};
    float rsum = 0.f;

    unsigned short* pw = Pl + wave * 1024;
    const int pwrow = l15 * 64;

    // stage K/V tile kt into buffer b (2 GLDS per wave, 8 waves cover tiles)
    auto stageKV = [&](int kt, int b) {
        {                                    // K tile [key][d]
            int c0 = wave * 64;
            int c  = c0 + lane;
            int r = c >> 3, pc = c & 7, q = pc ^ (r & 7);
            GLDS16(Kh + ((size_t)bh * S_LEN + kt * 64 + r) * HD + q * 8,
                   Ks + b * 4096 + c0 * 8);
        }
        {                                    // V tile [d][key]
            int c0 = wave * 64;
            int c  = c0 + lane;
            int d = c >> 3, pc = c & 7, q = pc ^ (d & 7);
            GLDS16(Vt + ((size_t)bh * HD + d) * S_LEN + kt * 64 + q * 8,
                   Vs + b * 4096 + c0 * 8);
        }
    };

    auto body = [&](int kt, int cb, bool pref) {
        if (pref) {
            stageKV(kt + 1, cb ^ 1);
            ASM_VMCNT(2);                    // cur's 2 landed; next's in flight
        } else {
            ASM_VMCNT(0);
        }
        ASM_BARRIER();

        const unsigned short* Kb = Ks + cb * 4096;
        const unsigned short* Vb = Vs + cb * 4096;

        const int kq = kt - 2 * qt;          // >=0: causal-boundary tile
        const int dw = (kq >= 0) ? (wave - (kq << 2)) : 7;
        if (dw >= 0) {
            const int nmax = dw < 3 ? dw : 3;
            const int qthr = dw * 16 + l15 - quad * 4;   // >=100 when full

            // ---- S^T: rows = keys, col = q. p = exp2(s - M0), pack to pw ----
            #pragma unroll
            for (int n = 0; n < 4; ++n) {
                int woff = pwrow + (((2 * n + (quad >> 1)) ^ (l15 & 7)) << 3) + (quad & 1) * 4;
                if (n <= nmax) {
                    int rk = n * 16 + l15;   // A-operand: lane = key row
                    int x = rk & 7;
                    bf16x8 kv0 = *(const bf16x8*)(Kb + rk * 64 + ((quad    ) ^ x) * 8);
                    bf16x8 kv1 = *(const bf16x8*)(Kb + rk * 64 + ((4 + quad) ^ x) * 8);
                    f32x4 t4 = (f32x4){-M0, -M0, -M0, -M0};
                    __builtin_amdgcn_s_setprio(1);
                    t4 = __builtin_amdgcn_mfma_f32_16x16x32_bf16(kv0, qf0, t4, 0, 0, 0);
                    t4 = __builtin_amdgcn_mfma_f32_16x16x32_bf16(kv1, qf1, t4, 0, 0, 0);
                    __builtin_amdgcn_s_setprio(0);
                    float p[4];
                    #pragma unroll
                    for (int r = 0; r < 4; ++r) {
                        p[r] = EXP2(t4[r]);
                        if ((n * 16 + r) > qthr) p[r] = 0.f;
                        rsum += p[r];
                    }
                    uint2 pk;
                    pk.x = pk_trunc(p[0], p[1]);
                    pk.y = pk_trunc(p[2], p[3]);
                    *(uint2*)(pw + woff) = pk;
                } else {
                    *(uint2*)(pw + woff) = (uint2){0u, 0u};
                }
            }

            // ---- Z^T += V^T P ----
            const int khmax = (dw >> 1) < 1 ? (dw >> 1) : 1;
            for (int kh = 0; kh <= khmax; ++kh) {
                bf16x8 pa = *(const bf16x8*)(pw + pwrow + ((kh * 4 + quad) ^ (l15 & 7)) * 8);
                __builtin_amdgcn_s_setprio(1);
                #pragma unroll
                for (int ni = 0; ni < 4; ++ni) {
                    int rd = ni * 16 + l15;  // A-operand: lane = d row
                    bf16x8 vb = *(const bf16x8*)(Vb + rd * 64 + ((kh * 4 + quad) ^ (rd & 7)) * 8);
                    Z[ni] = __builtin_amdgcn_mfma_f32_16x16x32_bf16(vb, pa, Z[ni], 0, 0, 0);
                }
                __builtin_amdgcn_s_setprio(0);
            }
        }
        ASM_BARRIER();                       // cur fully read before overwrite
    };

    stageKV(klo, 0);
    {
        int cnt = khi - klo + 1;
        int kt = klo;
        while (cnt >= 2) {                   // literal buffer bases in both bodies
            body(kt, 0, true);
            body(kt + 1, 1, cnt > 2);
            kt += 2; cnt -= 2;
        }
        if (cnt == 1) body(kt, 0, false);
    }

    // ---- combine quad partial sums (disjoint key subsets per quad) ----
    rsum += __shfl_xor(rsum, 16);
    rsum += __shfl_xor(rsum, 32);

    const int ql = wave * 16 + l15;          // q within 128-tile (lane = q column)
    if (part < 0) {
        const int b = bh >> 4, h = bh & (NH - 1);
        float inv = 1.f / rsum;
        size_t rowoff = (size_t)(b * S_LEN + q0 + ql) * DMODEL + h * HD;
        #pragma unroll
        for (int ni = 0; ni < 4; ++ni) {
            ushort4 o;
            o.x = f2bf(Z[ni][0] * inv);
            o.y = f2bf(Z[ni][1] * inv);
            o.z = f2bf(Z[ni][2] * inv);
            o.w = f2bf(Z[ni][3] * inv);
            *(ushort4*)(zb + rowoff + ni * 16 + quad * 4) = o;
        }
    } else {
        const int slot = (qt - 8) * 2 + part;        // 0..15
        float* zpo = Zp + ((size_t)(slot * 32 + bh) * 128 + ql) * 64;
        #pragma unroll
        for (int ni = 0; ni < 4; ++ni) {
            float4 st;
            st.x = Z[ni][0]; st.y = Z[ni][1]; st.z = Z[ni][2]; st.w = Z[ni][3];
            *(float4*)(zpo + ni * 16 + quad * 4) = st;
        }
        if (quad == 0)
            lp[(size_t)(slot * 32 + bh) * 128 + ql] = rsum;
    }
}

// ---------------------------------------------------------------------------
// Merge additive partials: zb = (Z0+Z1)/(l0+l1), grid (32 bh, 8 split qt)
// ---------------------------------------------------------------------------
__global__ __launch_bounds__(256) void attn_merge_kernel(
    const float* __restrict__ Zp, const float* __restrict__ lp,
    unsigned short* __restrict__ zb) {
    const int bh = blockIdx.x, qi = blockIdx.y, qt = 8 + qi;
    const int t = threadIdx.x;
    const int q = t >> 1;             // 0..127
    const int d0 = (t & 1) << 5;      // 0,32
    const int s0 = qi * 2, s1 = s0 + 1;
    float l = lp[(size_t)(s0 * 32 + bh) * 128 + q] +
              lp[(size_t)(s1 * 32 + bh) * 128 + q];
    float inv = 1.f / l;
    const float* z0 = Zp + ((size_t)(s0 * 32 + bh) * 128 + q) * 64 + d0;
    const float* z1 = Zp + ((size_t)(s1 * 32 + bh) * 128 + q) * 64 + d0;
    const int b = bh >> 4, h = bh & (NH - 1);
    unsigned short* o =
        zb + (size_t)(b * S_LEN + qt * 128 + q) * DMODEL + h * HD + d0;
    #pragma unroll
    for (int i = 0; i < 32; i += 4) {
        float4 a = *(const float4*)(z0 + i);
        float4 c = *(const float4*)(z1 + i);
        ushort4 ov;
        ov.x = f2bf((a.x + c.x) * inv);
        ov.y = f2bf((a.y + c.y) * inv);
        ov.z = f2bf((a.z + c.z) * inv);
        ov.w = f2bf((a.w + c.w) * inv);
        *(ushort4*)(o + i) = ov;
    }
}

// ---------------------------------------------------------------------------
extern "C" void kernel_launch(void* const* d_in, const int* in_sizes, int n_in,
                              void* d_out, int out_size, void* d_ws, size_t ws_size,
                              hipStream_t stream)
{
    const float* x     = (const float*)d_in[0];
    const float* w_qkv = (const float*)d_in[1];
    const float* b_qkv = (const float*)d_in[2];
    const float* w_out = (const float*)d_in[3];
    const float* b_out = (const float*)d_in[4];
    float* out = (float*)d_out;

    unsigned short* wsu   = (unsigned short*)d_ws;
    unsigned short* xb    = wsu;                       // 4096*1024
    unsigned short* wqkvT = xb    + (size_t)4194304;   // 3072*1024
    unsigned short* woutT = wqkvT + (size_t)3145728;   // 1024*1024
    unsigned short* Qt    = woutT + (size_t)1048576;   // 32*64*2048 (pre-scaled)
    unsigned short* Kh    = Qt    + (size_t)4194304;
    unsigned short* Vt    = Kh    + (size_t)4194304;
    unsigned short* zb    = Vt    + (size_t)4194304;   // 4096*1024
    float* Zp = (float*)(zb + (size_t)4194304);        // 16*32*128*64 fp32
    float* lp = Zp + (size_t)16 * 32 * 128 * 64;       // 16*32*128 fp32

    prep_kernel<<<dim3(8192), 256, 0, stream>>>(x, w_qkv, w_out, xb, wqkvT, woutT);

    gemm_qkv_kernel<<<dim3(768), 256, 0, stream>>>(
        xb, wqkvT, b_qkv, Qt, Kh, Vt);

    attn_mfma_kernel<<<dim3(2 * NH, 24), 512, 0, stream>>>(Qt, Kh, Vt, zb, Zp, lp);
    attn_merge_kernel<<<dim3(2 * NH, 8), 256, 0, stream>>>(Zp, lp, zb);

    gemm_out_kernel<<<dim3(512), 256, 0, stream>>>(
        zb, woutT, b_out, out);
}

// Round 5
// 169.040 us; speedup vs baseline: 1.3254x; 1.3254x over previous
//
#include <hip/hip_runtime.h>

#define S_LEN  2048
#define NH     16
#define HD     64
#define DMODEL 1024

using bf16x8 = __attribute__((ext_vector_type(8))) __bf16;
using f32x4  = __attribute__((ext_vector_type(4))) float;

__device__ __forceinline__ unsigned short f2bf(float f) {
    unsigned u = __float_as_uint(f);
    u += 0x7FFFu + ((u >> 16) & 1u);   // RNE
    return (unsigned short)(u >> 16);
}
// pack trunc(a)->lo, trunc(b)->hi in one v_perm
__device__ __forceinline__ unsigned pk_trunc(float lo, float hi) {
    return __builtin_amdgcn_perm(__float_as_uint(hi), __float_as_uint(lo), 0x07060302u);
}

// raw v_exp_f32 (2^x); avoids OCML fixup sequence. Underflow flushes to 0 (wanted).
#define EXP2(x) __builtin_amdgcn_exp2f(x)

// async global->LDS, 16B per lane; dest = wave-uniform base + lane*16
#define GLDS16(gsrc, ldst) \
    __builtin_amdgcn_global_load_lds((__attribute__((address_space(1))) void*)(gsrc), \
                                     (__attribute__((address_space(3))) void*)(ldst), 16, 0, 0)

#define WAIT_LGKM0() __builtin_amdgcn_s_waitcnt(0xC07F)   // lgkmcnt(0) only

// counted vmcnt + raw barrier (no implicit drain); memory clobber pins ordering
#define ASM_VMCNT(n)  asm volatile("s_waitcnt vmcnt(" #n ")" ::: "memory")
#define ASM_BARRIER() asm volatile("s_barrier" ::: "memory")

// ---------------------------------------------------------------------------
// Fused prep: x fp32->bf16 (blocks 0..4095), weight transpose+convert
// (blocks 4096..8191). No fences/atomics.
// ---------------------------------------------------------------------------
__global__ __launch_bounds__(256) void prep_kernel(
    const float* __restrict__ x, const float* __restrict__ w_qkv,
    const float* __restrict__ w_out,
    unsigned short* __restrict__ xb, unsigned short* __restrict__ wqkvT,
    unsigned short* __restrict__ woutT) {
    __shared__ float T[32][33];
    int bx = blockIdx.x;
    if (bx < 4096) {
        int idx = (bx * 256 + threadIdx.x) * 4;
        float4 v = *(const float4*)(x + idx);
        ushort4 o;
        o.x = f2bf(v.x); o.y = f2bf(v.y); o.z = f2bf(v.z); o.w = f2bf(v.w);
        *(ushort4*)(xb + idx) = o;
        return;
    }
    int tb = bx - 4096;
    int tcol = tb & 127, krow = tb >> 7;
    const float* in;
    unsigned short* out;
    int N, nbx;
    if (tcol < 96) { in = w_qkv; out = wqkvT; N = 3072; nbx = tcol; }
    else           { in = w_out; out = woutT; N = 1024; nbx = tcol - 96; }
    int r  = threadIdx.x >> 3;
    int c4 = (threadIdx.x & 7) * 4;
    int kbase = krow * 32, nbase = nbx * 32;
    float4 v = *(const float4*)(in + (size_t)(kbase + r) * N + nbase + c4);
    T[r][c4 + 0] = v.x; T[r][c4 + 1] = v.y; T[r][c4 + 2] = v.z; T[r][c4 + 3] = v.w;
    __syncthreads();
    ushort4 o;
    o.x = f2bf(T[c4 + 0][r]); o.y = f2bf(T[c4 + 1][r]);
    o.z = f2bf(T[c4 + 2][r]); o.w = f2bf(T[c4 + 3][r]);
    *(ushort4*)(out + (size_t)(nbase + r) * 1024 + kbase + c4) = o;
}

// ---------------------------------------------------------------------------
// MFMA NT GEMM mainloop, BK=64, tile 128 x (NI*32). One barrier per K-step:
//   { vmcnt(4); s_barrier; issue B(t+1); issue A(t+2); compute(t) }
// A triple-buffered (prefetch distance 2, covers L3/HBM latency),
// B double-buffered (distance 1, B strip is L2-resident by XCD swizzle).
// FIFO: iter t-1 issued [B(t), A(t+1)], iter t issues [B(t+1), A(t+2)];
// vmcnt(4) before the barrier completes B(t)+A(t+1), leaves A(t+2) in flight
// (never drains mid-loop; vmcnt(0) only on the final iteration).
// Buffer writes issued AFTER the barrier that retires their last readers.
// Fully unrolled (NT literal) so all LDS bases are compile-time.
// ---------------------------------------------------------------------------
template <int NI, int NT>
__device__ __forceinline__ void mfma_mainloop64(const unsigned short* __restrict__ A,
                                                const unsigned short* __restrict__ B,
                                                int m0, int n0,
                                                unsigned short* As, unsigned short* Bs,
                                                f32x4 acc[4][NI]) {
    constexpr int K = NT * 64;
    const int lane = threadIdx.x & 63, wave = threadIdx.x >> 6;
    const int quad = lane >> 4, l15 = lane & 15;
    const int wm0 = (wave >> 1) * 64, wn0 = (wave & 1) * (NI * 16);

    auto stageA = [&](int t) {           // 4 GLDS/thread -> As[t%3]
        unsigned short* Ad = As + (t % 3) * 8192;
        #pragma unroll
        for (int j = 0; j < 4; ++j) {
            int c0 = j * 256 + wave * 64;
            int c  = c0 + lane;
            int r = c >> 3, pc = c & 7, q = pc ^ (r & 7);
            GLDS16(A + (size_t)(m0 + r) * K + t * 64 + q * 8, Ad + c0 * 8);
        }
    };
    auto stageB = [&](int t) {           // NI GLDS/thread -> Bs[t&1]
        unsigned short* Bd = Bs + (t & 1) * (NI * 2048);
        #pragma unroll
        for (int j = 0; j < NI; ++j) {
            int c0 = j * 256 + wave * 64;
            int c  = c0 + lane;
            int r = c >> 3, pc = c & 7, q = pc ^ (r & 7);
            GLDS16(B + (size_t)(n0 + r) * K + t * 64 + q * 8, Bd + c0 * 8);
        }
    };

    // prologue: B0,A0,B1,A1,A2  (vmcnt(4) at t=0 completes B0..A1, A2 flies)
    stageB(0); stageA(0);
    stageB(1); stageA(1);
    stageA(2);

    #pragma unroll
    for (int t = 0; t < NT; ++t) {
        if (t < NT - 1) { ASM_VMCNT(4); } else { ASM_VMCNT(0); }
        ASM_BARRIER();                   // A(t),B(t) landed; prior readers done
        if (t >= 1) {                    // t=0 issues were in the prologue
            if (t + 1 < NT) stageB(t + 1);
            if (t + 2 < NT) stageA(t + 2);
        }

        const unsigned short* Ab = As + (t % 3) * 8192;
        const unsigned short* Bb = Bs + (t & 1) * (NI * 2048);
        bf16x8 af[2][4], bfr[2][NI];
        #pragma unroll
        for (int mi = 0; mi < 4; ++mi) {
            int r = wm0 + mi * 16 + l15, x = r & 7;
            af[0][mi] = *(const bf16x8*)(Ab + r * 64 + ((quad    ) ^ x) * 8);
            af[1][mi] = *(const bf16x8*)(Ab + r * 64 + ((4 + quad) ^ x) * 8);
        }
        #pragma unroll
        for (int ni = 0; ni < NI; ++ni) {
            int r = wn0 + ni * 16 + l15, x = r & 7;
            bfr[0][ni] = *(const bf16x8*)(Bb + r * 64 + ((quad    ) ^ x) * 8);
            bfr[1][ni] = *(const bf16x8*)(Bb + r * 64 + ((4 + quad) ^ x) * 8);
        }
        #pragma unroll
        for (int h = 0; h < 2; ++h)
            #pragma unroll
            for (int mi = 0; mi < 4; ++mi)
                #pragma unroll
                for (int ni = 0; ni < NI; ++ni)
                    acc[mi][ni] = __builtin_amdgcn_mfma_f32_16x16x32_bf16(
                        af[h][mi], bfr[h][ni], acc[mi][ni], 0, 0, 0);
    }
}

// ---------------------------------------------------------------------------
// GEMM1: qkv projection, 768 blocks, XCD-swizzled tiles: xcd = bid&7 owns
// n-strip [xcd*3, xcd*3+3) (B strip 768KB -> one L2). Epilogue: LDS
// transpose -> dwordx4 stores. Q -> Qt [bh][d][s] PRE-SCALED by
// 1/sqrt(64)*log2e, K -> Kh [bh][s][d], V -> Vt [bh][d][s].
// ---------------------------------------------------------------------------
__global__ __launch_bounds__(256) void gemm_qkv_kernel(
    const unsigned short* __restrict__ xb, const unsigned short* __restrict__ wT,
    const float* __restrict__ bias,
    unsigned short* __restrict__ Qt, unsigned short* __restrict__ Kh,
    unsigned short* __restrict__ Vt) {
    __shared__ __align__(16) unsigned short Sh[40960];  // As 3x8192 | Bs 2x8192 (80KB)
    unsigned short* As = Sh;
    unsigned short* Bs = Sh + 24576;

    f32x4 acc[4][4];
    #pragma unroll
    for (int i = 0; i < 4; ++i)
        #pragma unroll
        for (int j = 0; j < 4; ++j) acc[i][j] = (f32x4){0.f, 0.f, 0.f, 0.f};

    const int bid = blockIdx.x;
    const int xcd = bid & 7, slot = bid >> 3;          // slot 0..95
    const int nt = xcd * 3 + (slot % 3);               // 0..23
    const int mt = slot / 3;                           // 0..31
    const int m0 = mt * 128, n0 = nt * 128;
    mfma_mainloop64<4, 16>(xb, wT, m0, n0, As, Bs, acc);

    const int lane = threadIdx.x & 63, wave = threadIdx.x >> 6;
    const int quad = lane >> 4, l15 = lane & 15;
    const int wm0 = (wave >> 1) * 64, wn0 = (wave & 1) * 64;

    const int colbase = n0 + wn0;            // 64-aligned -> uniform t,h per wave
    const int t = colbase >> 10;
    const int h = (colbase >> 6) & (NH - 1);
    const float qscale = (t == 0) ? 0.125f * 1.44269504088896f : 1.0f;
    float bv[4];
    #pragma unroll
    for (int ni = 0; ni < 4; ++ni) bv[ni] = bias[colbase + ni * 16 + l15];

    __syncthreads();                         // everyone done reading As/Bs
    unsigned short* Lw = Sh + wave * 1536;   // per-wave scratch (3 KB)

    #pragma unroll
    for (int mi = 0; mi < 4; ++mi) {
        int mbase = m0 + wm0 + mi * 16;
        int b = mbase >> 11, sbase = mbase & (S_LEN - 1);
        if (t == 1) {
            // K: want [s][d] rows; Lw[r*72 + c]
            #pragma unroll
            for (int ni = 0; ni < 4; ++ni)
                #pragma unroll
                for (int r = 0; r < 4; ++r)
                    Lw[(quad * 4 + r) * 72 + ni * 16 + l15] =
                        f2bf(acc[mi][ni][r] + bv[ni]);
            WAIT_LGKM0();
            int rr = lane & 15, dc = (lane >> 4) * 16;
            uint4 v0 = *(const uint4*)(Lw + rr * 72 + dc);
            uint4 v1 = *(const uint4*)(Lw + rr * 72 + dc + 8);
            unsigned short* dst =
                Kh + ((size_t)(b * NH + h) * S_LEN + sbase + rr) * HD + dc;
            *(uint4*)dst = v0;
            *(uint4*)(dst + 8) = v1;
        } else {
            // Q/V: want [d][s] rows; Lw[c*24 + r]
            #pragma unroll
            for (int ni = 0; ni < 4; ++ni)
                #pragma unroll
                for (int r = 0; r < 4; ++r)
                    Lw[(ni * 16 + l15) * 24 + quad * 4 + r] =
                        f2bf((acc[mi][ni][r] + bv[ni]) * qscale);
            WAIT_LGKM0();
            int c = lane;                    // d within head
            uint4 v0 = *(const uint4*)(Lw + c * 24);
            uint4 v1 = *(const uint4*)(Lw + c * 24 + 8);
            unsigned short* base = (t == 0) ? Qt : Vt;
            unsigned short* dst =
                base + ((size_t)(b * NH + h) * HD + c) * S_LEN + sbase;
            *(uint4*)dst = v0;
            *(uint4*)(dst + 8) = v1;
        }
        WAIT_LGKM0();                        // stores consumed Lw before next mi
    }
}

// ---------------------------------------------------------------------------
// GEMM3: out = zb @ w_outT + b_out, fp32. 128x64 tiles -> 512 blocks (2/CU),
// XCD-swizzled: xcd owns n-tiles [2*xcd, 2*xcd+2) (B strip 256KB in L2).
// ---------------------------------------------------------------------------
__global__ __launch_bounds__(256) void gemm_out_kernel(
    const unsigned short* __restrict__ zb, const unsigned short* __restrict__ wT,
    const float* __restrict__ bias, float* __restrict__ out) {
    __shared__ __align__(16) unsigned short As[24576], Bs[8192];  // 64KB
    f32x4 acc[4][2];
    #pragma unroll
    for (int i = 0; i < 4; ++i)
        #pragma unroll
        for (int j = 0; j < 2; ++j) acc[i][j] = (f32x4){0.f, 0.f, 0.f, 0.f};

    const int bid = blockIdx.x;
    const int xcd = bid & 7, slot = bid >> 3;          // slot 0..63
    const int nt = xcd * 2 + (slot & 1);               // 0..15 (64-wide)
    const int mt = slot >> 1;                          // 0..31
    const int m0 = mt * 128, n0 = nt * 64;
    mfma_mainloop64<2, 16>(zb, wT, m0, n0, As, Bs, acc);

    const int lane = threadIdx.x & 63, wave = threadIdx.x >> 6;
    const int quad = lane >> 4, l15 = lane & 15;
    const int wm0 = (wave >> 1) * 64, wn0 = (wave & 1) * 32;
    #pragma unroll
    for (int mi = 0; mi < 4; ++mi) {
        #pragma unroll
        for (int ni = 0; ni < 2; ++ni) {
            int col = n0 + wn0 + ni * 16 + l15;
            float bvv = bias[col];
            #pragma unroll
            for (int r = 0; r < 4; ++r)
                out[(size_t)(m0 + wm0 + mi * 16 + quad * 4 + r) * DMODEL + col] =
                    acc[mi][ni][r] + bvv;
        }
    }
}

// ---------------------------------------------------------------------------
// Balanced causal schedule for QBLK=128: 24 entries {qt, kt_lo, kt_hi, part},
// size-descending. qt 8..15 split into halves (part 0/1); qt 0..7 unsplit.
// ---------------------------------------------------------------------------
__device__ const int g_sched[24 * 4] = {
    15,0,15,0,  15,16,31,1,  7,0,15,-1,
    14,0,14,0,  14,15,29,1,  6,0,13,-1,
    13,0,13,0,  13,14,27,1,
    12,0,12,0,  12,13,25,1,  5,0,11,-1,
    11,0,11,0,  11,12,23,1,
    10,0,10,0,  10,11,21,1,  4,0,9,-1,
     9,0,9,0,    9,10,19,1,
     8,0,8,0,    8,9,17,1,   3,0,7,-1,
     2,0,5,-1,   1,0,3,-1,   0,0,1,-1
};

// ---------------------------------------------------------------------------
// Flash attention, S^T orientation: S^T = K Q^T, Z^T = V^T P. Fixed-max
// softmax (Q pre-scaled, acc init -M0). QBLK=128, 8 waves; K/V LDS
// double-buffered, counted-vmcnt 2-phase pipeline, kt-loop unrolled by 2
// (literal buffer bases), raw v_exp_f32, setprio around MFMA clusters.
// Causal: for k-tile kt, kq = kt-2*qt; dw = wave-4*kq (<0 => wave fully
// masked, skip); nmax=min(dw,3), khmax=min(dw>>1,1).
// ---------------------------------------------------------------------------
__global__ __launch_bounds__(512) void attn_mfma_kernel(
    const unsigned short* __restrict__ Qt, const unsigned short* __restrict__ Kh,
    const unsigned short* __restrict__ Vt, unsigned short* __restrict__ zb,
    float* __restrict__ Zp, float* __restrict__ lp) {
    __shared__ __align__(16) unsigned short Ks[2 * 64 * 64]; // [key][d], swizzled, dbuf
    __shared__ __align__(16) unsigned short Vs[2 * 64 * 64]; // [d][key], swizzled, dbuf
    __shared__ __align__(16) unsigned short Pl[8 * 16 * 64]; // per-wave P, swizzled

    const int lane = threadIdx.x & 63, wave = threadIdx.x >> 6;   // wave 0..7
    const int quad = lane >> 4, l15 = lane & 15;
    const int bh = blockIdx.x;
    const int qt   = g_sched[blockIdx.y * 4 + 0];
    const int klo  = g_sched[blockIdx.y * 4 + 1];
    const int khi  = g_sched[blockIdx.y * 4 + 2];
    const int part = g_sched[blockIdx.y * 4 + 3];
    const int q0 = qt * 128;
    const float M0 = 12.0f;                  // fixed max (log2 domain)

    // ---- Q B-frags from Qt [bh][d][s] (pre-scaled): lane = q column ----
    bf16x8 qf0, qf1;
    {
        const unsigned short* qb = Qt + (size_t)bh * HD * S_LEN + q0 + wave * 16 + l15;
        union { bf16x8 v; unsigned short u[8]; } u0, u1;
        #pragma unroll
        for (int j = 0; j < 8; ++j) {
            u0.u[j] = qb[(quad * 8 + j) * S_LEN];
            u1.u[j] = qb[(32 + quad * 8 + j) * S_LEN];
        }
        qf0 = u0.v; qf1 = u1.v;
    }

    f32x4 Z[4];
    #pragma unroll
    for (int i = 0; i < 4; ++i) Z[i] = (f32x4){0.f, 0.f, 0.f, 0.f};
    float rsum = 0.f;

    unsigned short* pw = Pl + wave * 1024;
    const int pwrow = l15 * 64;

    // stage K/V tile kt into buffer b (2 GLDS per wave, 8 waves cover tiles)
    auto stageKV = [&](int kt, int b) {
        {                                    // K tile [key][d]
            int c0 = wave * 64;
            int c  = c0 + lane;
            int r = c >> 3, pc = c & 7, q = pc ^ (r & 7);
            GLDS16(Kh + ((size_t)bh * S_LEN + kt * 64 + r) * HD + q * 8,
                   Ks + b * 4096 + c0 * 8);
        }
        {                                    // V tile [d][key]
            int c0 = wave * 64;
            int c  = c0 + lane;
            int d = c >> 3, pc = c & 7, q = pc ^ (d & 7);
            GLDS16(Vt + ((size_t)bh * HD + d) * S_LEN + kt * 64 + q * 8,
                   Vs + b * 4096 + c0 * 8);
        }
    };

    auto body = [&](int kt, int cb, bool pref) {
        if (pref) {
            stageKV(kt + 1, cb ^ 1);
            ASM_VMCNT(2);                    // cur's 2 landed; next's in flight
        } else {
            ASM_VMCNT(0);
        }
        ASM_BARRIER();

        const unsigned short* Kb = Ks + cb * 4096;
        const unsigned short* Vb = Vs + cb * 4096;

        const int kq = kt - 2 * qt;          // >=0: causal-boundary tile
        const int dw = (kq >= 0) ? (wave - (kq << 2)) : 7;
        if (dw >= 0) {
            const int nmax = dw < 3 ? dw : 3;
            const int qthr = dw * 16 + l15 - quad * 4;   // >=100 when full

            // ---- S^T: rows = keys, col = q. p = exp2(s - M0), pack to pw ----
            #pragma unroll
            for (int n = 0; n < 4; ++n) {
                int woff = pwrow + (((2 * n + (quad >> 1)) ^ (l15 & 7)) << 3) + (quad & 1) * 4;
                if (n <= nmax) {
                    int rk = n * 16 + l15;   // A-operand: lane = key row
                    int x = rk & 7;
                    bf16x8 kv0 = *(const bf16x8*)(Kb + rk * 64 + ((quad    ) ^ x) * 8);
                    bf16x8 kv1 = *(const bf16x8*)(Kb + rk * 64 + ((4 + quad) ^ x) * 8);
                    f32x4 t4 = (f32x4){-M0, -M0, -M0, -M0};
                    __builtin_amdgcn_s_setprio(1);
                    t4 = __builtin_amdgcn_mfma_f32_16x16x32_bf16(kv0, qf0, t4, 0, 0, 0);
                    t4 = __builtin_amdgcn_mfma_f32_16x16x32_bf16(kv1, qf1, t4, 0, 0, 0);
                    __builtin_amdgcn_s_setprio(0);
                    float p[4];
                    #pragma unroll
                    for (int r = 0; r < 4; ++r) {
                        p[r] = EXP2(t4[r]);
                        if ((n * 16 + r) > qthr) p[r] = 0.f;
                        rsum += p[r];
                    }
                    uint2 pk;
                    pk.x = pk_trunc(p[0], p[1]);
                    pk.y = pk_trunc(p[2], p[3]);
                    *(uint2*)(pw + woff) = pk;
                } else {
                    *(uint2*)(pw + woff) = (uint2){0u, 0u};
                }
            }

            // ---- Z^T += V^T P ----
            const int khmax = (dw >> 1) < 1 ? (dw >> 1) : 1;
            for (int kh = 0; kh <= khmax; ++kh) {
                bf16x8 pa = *(const bf16x8*)(pw + pwrow + ((kh * 4 + quad) ^ (l15 & 7)) * 8);
                __builtin_amdgcn_s_setprio(1);
                #pragma unroll
                for (int ni = 0; ni < 4; ++ni) {
                    int rd = ni * 16 + l15;  // A-operand: lane = d row
                    bf16x8 vb = *(const bf16x8*)(Vb + rd * 64 + ((kh * 4 + quad) ^ (rd & 7)) * 8);
                    Z[ni] = __builtin_amdgcn_mfma_f32_16x16x32_bf16(vb, pa, Z[ni], 0, 0, 0);
                }
                __builtin_amdgcn_s_setprio(0);
            }
        }
        ASM_BARRIER();                       // cur fully read before overwrite
    };

    stageKV(klo, 0);
    {
        int cnt = khi - klo + 1;
        int kt = klo;
        while (cnt >= 2) {                   // literal buffer bases in both bodies
            body(kt, 0, true);
            body(kt + 1, 1, cnt > 2);
            kt += 2; cnt -= 2;
        }
        if (cnt == 1) body(kt, 0, false);
    }

    // ---- combine quad partial sums (disjoint key subsets per quad) ----
    rsum += __shfl_xor(rsum, 16);
    rsum += __shfl_xor(rsum, 32);

    const int ql = wave * 16 + l15;          // q within 128-tile (lane = q column)
    if (part < 0) {
        const int b = bh >> 4, h = bh & (NH - 1);
        float inv = 1.f / rsum;
        size_t rowoff = (size_t)(b * S_LEN + q0 + ql) * DMODEL + h * HD;
        #pragma unroll
        for (int ni = 0; ni < 4; ++ni) {
            ushort4 o;
            o.x = f2bf(Z[ni][0] * inv);
            o.y = f2bf(Z[ni][1] * inv);
            o.z = f2bf(Z[ni][2] * inv);
            o.w = f2bf(Z[ni][3] * inv);
            *(ushort4*)(zb + rowoff + ni * 16 + quad * 4) = o;
        }
    } else {
        const int slot = (qt - 8) * 2 + part;        // 0..15
        float* zpo = Zp + ((size_t)(slot * 32 + bh) * 128 + ql) * 64;
        #pragma unroll
        for (int ni = 0; ni < 4; ++ni) {
            float4 st;
            st.x = Z[ni][0]; st.y = Z[ni][1]; st.z = Z[ni][2]; st.w = Z[ni][3];
            *(float4*)(zpo + ni * 16 + quad * 4) = st;
        }
        if (quad == 0)
            lp[(size_t)(slot * 32 + bh) * 128 + ql] = rsum;
    }
}

// ---------------------------------------------------------------------------
// Merge additive partials: zb = (Z0+Z1)/(l0+l1), grid (32 bh, 8 split qt)
// ---------------------------------------------------------------------------
__global__ __launch_bounds__(256) void attn_merge_kernel(
    const float* __restrict__ Zp, const float* __restrict__ lp,
    unsigned short* __restrict__ zb) {
    const int bh = blockIdx.x, qi = blockIdx.y, qt = 8 + qi;
    const int t = threadIdx.x;
    const int q = t >> 1;             // 0..127
    const int d0 = (t & 1) << 5;      // 0,32
    const int s0 = qi * 2, s1 = s0 + 1;
    float l = lp[(size_t)(s0 * 32 + bh) * 128 + q] +
              lp[(size_t)(s1 * 32 + bh) * 128 + q];
    float inv = 1.f / l;
    const float* z0 = Zp + ((size_t)(s0 * 32 + bh) * 128 + q) * 64 + d0;
    const float* z1 = Zp + ((size_t)(s1 * 32 + bh) * 128 + q) * 64 + d0;
    const int b = bh >> 4, h = bh & (NH - 1);
    unsigned short* o =
        zb + (size_t)(b * S_LEN + qt * 128 + q) * DMODEL + h * HD + d0;
    #pragma unroll
    for (int i = 0; i < 32; i += 4) {
        float4 a = *(const float4*)(z0 + i);
        float4 c = *(const float4*)(z1 + i);
        ushort4 ov;
        ov.x = f2bf((a.x + c.x) * inv);
        ov.y = f2bf((a.y + c.y) * inv);
        ov.z = f2bf((a.z + c.z) * inv);
        ov.w = f2bf((a.w + c.w) * inv);
        *(ushort4*)(o + i) = ov;
    }
}

// ---------------------------------------------------------------------------
extern "C" void kernel_launch(void* const* d_in, const int* in_sizes, int n_in,
                              void* d_out, int out_size, void* d_ws, size_t ws_size,
                              hipStream_t stream)
{
    const float* x     = (const float*)d_in[0];
    const float* w_qkv = (const float*)d_in[1];
    const float* b_qkv = (const float*)d_in[2];
    const float* w_out = (const float*)d_in[3];
    const float* b_out = (const float*)d_in[4];
    float* out = (float*)d_out;

    unsigned short* wsu   = (unsigned short*)d_ws;
    unsigned short* xb    = wsu;                       // 4096*1024
    unsigned short* wqkvT = xb    + (size_t)4194304;   // 3072*1024
    unsigned short* woutT = wqkvT + (size_t)3145728;   // 1024*1024
    unsigned short* Qt    = woutT + (size_t)1048576;   // 32*64*2048 (pre-scaled)
    unsigned short* Kh    = Qt    + (size_t)4194304;
    unsigned short* Vt    = Kh    + (size_t)4194304;
    unsigned short* zb    = Vt    + (size_t)4194304;   // 4096*1024
    float* Zp = (float*)(zb + (size_t)4194304);        // 16*32*128*64 fp32
    float* lp = Zp + (size_t)16 * 32 * 128 * 64;       // 16*32*128 fp32

    prep_kernel<<<dim3(8192), 256, 0, stream>>>(x, w_qkv, w_out, xb, wqkvT, woutT);

    gemm_qkv_kernel<<<dim3(768), 256, 0, stream>>>(
        xb, wqkvT, b_qkv, Qt, Kh, Vt);

    attn_mfma_kernel<<<dim3(2 * NH, 24), 512, 0, stream>>>(Qt, Kh, Vt, zb, Zp, lp);
    attn_merge_kernel<<<dim3(2 * NH, 8), 256, 0, stream>>>(Zp, lp, zb);

    gemm_out_kernel<<<dim3(512), 256, 0, stream>>>(
        zb, woutT, b_out, out);
}